// Round 1
// baseline (410.982 us; speedup 1.0000x reference)
//
#include <hip/hip_runtime.h>

typedef unsigned short u16;
using frag16 = __attribute__((ext_vector_type(8))) short;   // 8 x bf16 (4 VGPRs)
using facc   = __attribute__((ext_vector_type(4))) float;   // 4 x fp32 acc

#define DEV static __device__ __forceinline__

DEV u16 f2bf(float f) {
  union { float f; unsigned u; } v; v.f = f;
  unsigned r = v.u + 0x7fffu + ((v.u >> 16) & 1u);
  return (u16)(r >> 16);
}
DEV float bf2f(u16 b) {
  union { unsigned u; float f; } v; v.u = ((unsigned)b) << 16;
  return v.f;
}

// ---------------- weight transpose + bf16 convert: W[K,N] -> WT[N,K] ----------
__global__ void wtrans_kernel(const float* __restrict__ W, u16* __restrict__ WT,
                              int K, int N) {
  int id = blockIdx.x * 256 + threadIdx.x;
  if (id >= K * N) return;
  int n = id / K, k = id - n * K;
  WT[id] = f2bf(W[k * N + n]);
}

// ---------------- x fp32 -> bf16 ---------------------------------------------
__global__ void cvt_kernel(const float4* __restrict__ x, u16* __restrict__ xb, int n4) {
  int id = blockIdx.x * 256 + threadIdx.x;
  if (id >= n4) return;
  float4 v = x[id];
  ushort4 o;
  o.x = f2bf(v.x); o.y = f2bf(v.y); o.z = f2bf(v.z); o.w = f2bf(v.w);
  *(ushort4*)(xb + (size_t)id * 4) = o;
}

// ---------------- gate: gctx = bf16(ctx * sigmoid(relu(ctx@W1+b1)@W2+b2)) -----
__global__ __launch_bounds__(256) void gate_kernel(const float* __restrict__ ctx,
    const float* __restrict__ W1, const float* __restrict__ b1,
    const float* __restrict__ W2, const float* __restrict__ b2,
    u16* __restrict__ gctx) {
  int wave = threadIdx.x >> 6, lane = threadIdx.x & 63;
  int row = blockIdx.x * 4 + wave;            // 8192 rows total
  __shared__ float sc[4][64];
  float cv = ctx[(size_t)row * 64 + lane];
  sc[wave][lane] = cv;
  __syncthreads();
  float h = 0.f;
  if (lane < 32) {
    h = b1[lane];
    #pragma unroll
    for (int i = 0; i < 64; ++i) h += sc[wave][i] * W1[i * 32 + lane];
    h = fmaxf(h, 0.f) * W2[lane];
  }
  #pragma unroll
  for (int off = 32; off; off >>= 1) h += __shfl_xor(h, off);
  float g = 1.f / (1.f + __expf(-(h + b2[0])));
  gctx[(size_t)row * 64 + lane] = f2bf(cv * g);
}

// ---------------- generic MFMA GEMM: C[M,N] = A[M,K](bf16) @ BT[N,K](bf16)^T --
// MODE 0: bf16 out, scaled.  MODE 1: transposed-packed out (V^T layout).
// MODE 2: fp32 out + bias.
template<int MODE>
__global__ __launch_bounds__(256) void gemm_bt(const u16* __restrict__ A,
    const u16* __restrict__ BT, void* __restrict__ Cp,
    const float* __restrict__ bias, int M, int N, int K, float scale) {
  int lane = threadIdx.x & 63, wave = threadIdx.x >> 6;
  int quad = lane >> 4, l16 = lane & 15;
  int wr = wave >> 1, wc = wave & 1;
  int rowBase = blockIdx.y * 64 + wr * 32;
  int colBase = blockIdx.x * 64 + wc * 32;
  facc acc[2][2] = {};
  const u16* a0 = A + (size_t)(rowBase + l16) * K + quad * 8;
  const u16* a1 = a0 + (size_t)16 * K;
  const u16* b0 = BT + (size_t)(colBase + l16) * K + quad * 8;
  const u16* b1p = b0 + (size_t)16 * K;
  for (int kk = 0; kk < K; kk += 32) {
    frag16 af0 = *(const frag16*)(a0 + kk);
    frag16 af1 = *(const frag16*)(a1 + kk);
    frag16 bf0 = *(const frag16*)(b0 + kk);
    frag16 bf1 = *(const frag16*)(b1p + kk);
    acc[0][0] = __builtin_amdgcn_mfma_f32_16x16x32_bf16(af0, bf0, acc[0][0], 0, 0, 0);
    acc[0][1] = __builtin_amdgcn_mfma_f32_16x16x32_bf16(af0, bf1, acc[0][1], 0, 0, 0);
    acc[1][0] = __builtin_amdgcn_mfma_f32_16x16x32_bf16(af1, bf0, acc[1][0], 0, 0, 0);
    acc[1][1] = __builtin_amdgcn_mfma_f32_16x16x32_bf16(af1, bf1, acc[1][1], 0, 0, 0);
  }
  #pragma unroll
  for (int rt = 0; rt < 2; ++rt) {
    #pragma unroll
    for (int ct = 0; ct < 2; ++ct) {
      int col = colBase + ct * 16 + l16;
      int r0 = rowBase + rt * 16 + quad * 4;
      if (MODE == 0) {
        u16* C = (u16*)Cp;
        #pragma unroll
        for (int r = 0; r < 4; ++r)
          C[(size_t)(r0 + r) * N + col] = f2bf(acc[rt][ct][r] * scale);
      } else if (MODE == 1) {
        // store C^T packed: addr = (b*512 + col)*2048 + (row within batch)
        u16* C = (u16*)Cp;
        int bb = r0 >> 11, ml = r0 & 2047;
        ushort4 o;
        o.x = f2bf(acc[rt][ct][0]); o.y = f2bf(acc[rt][ct][1]);
        o.z = f2bf(acc[rt][ct][2]); o.w = f2bf(acc[rt][ct][3]);
        *(ushort4*)(C + ((size_t)(bb * 512 + col) * 2048 + ml)) = o;
      } else {
        float* C = (float*)Cp;
        float bv = bias ? bias[col] : 0.f;
        #pragma unroll
        for (int r = 0; r < 4; ++r)
          C[(size_t)(r0 + r) * N + col] = acc[rt][ct][r] + bv;
      }
    }
  }
}

// ---------------- flash attention ---------------------------------------------
// q: [B,N,H*D] bf16 (pre-scaled by 1/8), k: [B,M,H*D] bf16,
// vT: [(b*512 + h*64 + d), M] bf16, o: [B,N,H*D] bf16
__global__ __launch_bounds__(256) void attn_kernel(const u16* __restrict__ qb,
    const u16* __restrict__ kb, const u16* __restrict__ vT,
    u16* __restrict__ ob) {
  const int lane = threadIdx.x & 63, wave = threadIdx.x >> 6;
  const int quad = lane >> 4, l16 = lane & 15;
  int bid = blockIdx.x;
  int bh = bid >> 5;          // 32 q-tiles (of 64 rows) per (b,h)
  int qt = bid & 31;
  int b = bh >> 3, h = bh & 7;
  int qrow = qt * 64 + wave * 16;

  __shared__ __align__(16) u16 pl[4][16][32];

  const u16* qp = qb + ((size_t)(b * 2048 + qrow + l16) * 512 + h * 64) + quad * 8;
  frag16 qf0 = *(const frag16*)qp;
  frag16 qf1 = *(const frag16*)(qp + 32);

  facc O[4] = {};
  float mr[4] = {-1e30f, -1e30f, -1e30f, -1e30f};
  float lr[4] = {0.f, 0.f, 0.f, 0.f};

  const u16* kbase = kb + ((size_t)(b * 2048 + l16) * 512 + h * 64) + quad * 8;
  const u16* vbase = vT + ((size_t)(b * 512 + h * 64 + l16) * 2048) + quad * 8;

  for (int j0 = 0; j0 < 2048; j0 += 32) {
    const u16* kp = kbase + (size_t)j0 * 512;
    frag16 k00 = *(const frag16*)kp;                  // cols j0..j0+15, d 0..31 half
    frag16 k01 = *(const frag16*)(kp + 32);           // d 32..63 half
    frag16 k10 = *(const frag16*)(kp + 16 * 512);     // cols j0+16..j0+31
    frag16 k11 = *(const frag16*)(kp + 16 * 512 + 32);
    facc z = {};
    facc c0 = __builtin_amdgcn_mfma_f32_16x16x32_bf16(qf0, k00, z, 0, 0, 0);
    c0 = __builtin_amdgcn_mfma_f32_16x16x32_bf16(qf1, k01, c0, 0, 0, 0);
    facc c1 = __builtin_amdgcn_mfma_f32_16x16x32_bf16(qf0, k10, z, 0, 0, 0);
    c1 = __builtin_amdgcn_mfma_f32_16x16x32_bf16(qf1, k11, c1, 0, 0, 0);

    // row max over the 32 keys (reduce across the 16 lanes sharing a quad)
    float mx[4], al[4], rs[4];
    #pragma unroll
    for (int r = 0; r < 4; ++r) mx[r] = fmaxf(c0[r], c1[r]);
    #pragma unroll
    for (int off = 1; off < 16; off <<= 1) {
      #pragma unroll
      for (int r = 0; r < 4; ++r) mx[r] = fmaxf(mx[r], __shfl_xor(mx[r], off));
    }
    #pragma unroll
    for (int r = 0; r < 4; ++r) {
      float mn = fmaxf(mr[r], mx[r]);
      al[r] = __expf(mr[r] - mn);
      mr[r] = mn;
      u16 u0 = f2bf(__expf(c0[r] - mn));
      u16 u1 = f2bf(__expf(c1[r] - mn));
      pl[wave][quad * 4 + r][l16] = u0;
      pl[wave][quad * 4 + r][l16 + 16] = u1;
      rs[r] = bf2f(u0) + bf2f(u1);
    }
    #pragma unroll
    for (int off = 1; off < 16; off <<= 1) {
      #pragma unroll
      for (int r = 0; r < 4; ++r) rs[r] += __shfl_xor(rs[r], off);
    }
    #pragma unroll
    for (int r = 0; r < 4; ++r) lr[r] = lr[r] * al[r] + rs[r];
    #pragma unroll
    for (int ct = 0; ct < 4; ++ct) {
      #pragma unroll
      for (int r = 0; r < 4; ++r) O[ct][r] *= al[r];
    }
    __syncthreads();
    frag16 pf = *(const frag16*)&pl[wave][l16][quad * 8];   // A-layout read
    #pragma unroll
    for (int ct = 0; ct < 4; ++ct) {
      frag16 vf = *(const frag16*)(vbase + (size_t)(ct * 16) * 2048 + j0);
      O[ct] = __builtin_amdgcn_mfma_f32_16x16x32_bf16(pf, vf, O[ct], 0, 0, 0);
    }
    __syncthreads();
  }
  #pragma unroll
  for (int ct = 0; ct < 4; ++ct) {
    #pragma unroll
    for (int r = 0; r < 4; ++r) {
      float o = O[ct][r] / lr[r];
      int row = qrow + quad * 4 + r;
      ob[(size_t)(b * 2048 + row) * 512 + h * 64 + ct * 16 + l16] = f2bf(o);
    }
  }
}

// ---------------- launch ------------------------------------------------------
extern "C" void kernel_launch(void* const* d_in, const int* in_sizes, int n_in,
                              void* d_out, int out_size, void* d_ws, size_t ws_size,
                              hipStream_t stream) {
  const float* x   = (const float*)d_in[0];
  const float* ctx = (const float*)d_in[1];
  const float* Wq  = (const float*)d_in[2];
  const float* Wk  = (const float*)d_in[3];
  const float* Wv  = (const float*)d_in[4];
  const float* W1  = (const float*)d_in[5];
  const float* b1  = (const float*)d_in[6];
  const float* W2  = (const float*)d_in[7];
  const float* b2  = (const float*)d_in[8];
  const float* Wo  = (const float*)d_in[9];
  const float* bo  = (const float*)d_in[10];
  float* out = (float*)d_out;

  char* ws = (char*)d_ws;
  size_t off = 0;
  auto alloc = [&](size_t bytes) {
    char* p = ws + off;
    off += (bytes + 255) & ~(size_t)255;
    return p;
  };
  u16* xb   = (u16*)alloc(8192ull * 512 * 2);
  u16* qb   = (u16*)alloc(8192ull * 512 * 2);
  u16* kb   = (u16*)alloc(8192ull * 512 * 2);
  u16* vT   = (u16*)alloc(8192ull * 512 * 2);
  u16* ob   = (u16*)alloc(8192ull * 512 * 2);
  u16* gctx = (u16*)alloc(8192ull * 64 * 2);
  u16* WqT  = (u16*)alloc(512ull * 512 * 2);
  u16* WkT  = (u16*)alloc(512ull * 64 * 2);
  u16* WvT  = (u16*)alloc(512ull * 64 * 2);
  u16* WoT  = (u16*)alloc(512ull * 512 * 2);

  wtrans_kernel<<<(512 * 512 + 255) / 256, 256, 0, stream>>>(Wq, WqT, 512, 512);
  wtrans_kernel<<<(64 * 512 + 255) / 256, 256, 0, stream>>>(Wk, WkT, 64, 512);
  wtrans_kernel<<<(64 * 512 + 255) / 256, 256, 0, stream>>>(Wv, WvT, 64, 512);
  wtrans_kernel<<<(512 * 512 + 255) / 256, 256, 0, stream>>>(Wo, WoT, 512, 512);
  cvt_kernel<<<(8192 * 512 / 4 + 255) / 256, 256, 0, stream>>>((const float4*)x, xb, 8192 * 512 / 4);
  gate_kernel<<<2048, 256, 0, stream>>>(ctx, W1, b1, W2, b2, gctx);

  // q = x @ Wq, scaled by 1/sqrt(64)
  gemm_bt<0><<<dim3(8, 128), 256, 0, stream>>>(xb, WqT, qb, nullptr, 8192, 512, 512, 0.125f);
  // k = gctx @ Wk
  gemm_bt<0><<<dim3(8, 128), 256, 0, stream>>>(gctx, WkT, kb, nullptr, 8192, 512, 64, 1.f);
  // vT = (gctx @ Wv)^T packed per (b,h,d)
  gemm_bt<1><<<dim3(8, 128), 256, 0, stream>>>(gctx, WvT, vT, nullptr, 8192, 512, 64, 1.f);

  attn_kernel<<<1024, 256, 0, stream>>>(qb, kb, vT, ob);

  // out = ob @ Wo + bo  (fp32)
  gemm_bt<2><<<dim3(8, 128), 256, 0, stream>>>(ob, WoT, out, bo, 8192, 512, 512, 1.f);
}

// Round 2
// 408.624 us; speedup vs baseline: 1.0058x; 1.0058x over previous
//
#include <hip/hip_runtime.h>

typedef unsigned short u16;
using frag16 = __attribute__((ext_vector_type(8))) short;   // 8 x bf16 (4 VGPRs)
using facc   = __attribute__((ext_vector_type(4))) float;   // 4 x fp32 acc

#define DEV static __device__ __forceinline__

DEV u16 f2bf(float f) {
  union { float f; unsigned u; } v; v.f = f;
  unsigned r = v.u + 0x7fffu + ((v.u >> 16) & 1u);
  return (u16)(r >> 16);
}
DEV float bf2f(u16 b) {
  union { unsigned u; float f; } v; v.u = ((unsigned)b) << 16;
  return v.f;
}
DEV unsigned fbits(float f) {
  union { float f; unsigned u; } v; v.f = f;
  return v.u;
}

// ---------------- weight transpose + bf16 convert: W[K,N] -> WT[N,K] ----------
__global__ void wtrans_kernel(const float* __restrict__ W, u16* __restrict__ WT,
                              int K, int N) {
  int id = blockIdx.x * 256 + threadIdx.x;
  if (id >= K * N) return;
  int n = id / K, k = id - n * K;
  WT[id] = f2bf(W[k * N + n]);
}

// ---------------- x fp32 -> bf16 ---------------------------------------------
__global__ void cvt_kernel(const float4* __restrict__ x, u16* __restrict__ xb, int n4) {
  int id = blockIdx.x * 256 + threadIdx.x;
  if (id >= n4) return;
  float4 v = x[id];
  ushort4 o;
  o.x = f2bf(v.x); o.y = f2bf(v.y); o.z = f2bf(v.z); o.w = f2bf(v.w);
  *(ushort4*)(xb + (size_t)id * 4) = o;
}

// ---------------- gate: gctx = bf16(ctx * sigmoid(relu(ctx@W1+b1)@W2+b2)) -----
__global__ __launch_bounds__(256) void gate_kernel(const float* __restrict__ ctx,
    const float* __restrict__ W1, const float* __restrict__ b1,
    const float* __restrict__ W2, const float* __restrict__ b2,
    u16* __restrict__ gctx) {
  int wave = threadIdx.x >> 6, lane = threadIdx.x & 63;
  int row = blockIdx.x * 4 + wave;            // 8192 rows total
  __shared__ float sc[4][64];
  float cv = ctx[(size_t)row * 64 + lane];
  sc[wave][lane] = cv;
  __syncthreads();
  float h = 0.f;
  if (lane < 32) {
    h = b1[lane];
    #pragma unroll
    for (int i = 0; i < 64; ++i) h += sc[wave][i] * W1[i * 32 + lane];
    h = fmaxf(h, 0.f) * W2[lane];
  }
  #pragma unroll
  for (int off = 32; off; off >>= 1) h += __shfl_xor(h, off);
  float g = 1.f / (1.f + __expf(-(h + b2[0])));
  gctx[(size_t)row * 64 + lane] = f2bf(cv * g);
}

// ---------------- generic MFMA GEMM: C[M,N] = A[M,K](bf16) @ BT[N,K](bf16)^T --
// MODE 0: bf16 out, scaled.  MODE 1: transposed-packed out (V^T layout).
// MODE 2: fp32 out + bias.
template<int MODE>
__global__ __launch_bounds__(256) void gemm_bt(const u16* __restrict__ A,
    const u16* __restrict__ BT, void* __restrict__ Cp,
    const float* __restrict__ bias, int M, int N, int K, float scale) {
  int lane = threadIdx.x & 63, wave = threadIdx.x >> 6;
  int quad = lane >> 4, l16 = lane & 15;
  int wr = wave >> 1, wc = wave & 1;
  int rowBase = blockIdx.y * 64 + wr * 32;
  int colBase = blockIdx.x * 64 + wc * 32;
  facc acc[2][2] = {};
  const u16* a0 = A + (size_t)(rowBase + l16) * K + quad * 8;
  const u16* a1 = a0 + (size_t)16 * K;
  const u16* b0 = BT + (size_t)(colBase + l16) * K + quad * 8;
  const u16* b1p = b0 + (size_t)16 * K;
  for (int kk = 0; kk < K; kk += 32) {
    frag16 af0 = *(const frag16*)(a0 + kk);
    frag16 af1 = *(const frag16*)(a1 + kk);
    frag16 bf0 = *(const frag16*)(b0 + kk);
    frag16 bf1 = *(const frag16*)(b1p + kk);
    acc[0][0] = __builtin_amdgcn_mfma_f32_16x16x32_bf16(af0, bf0, acc[0][0], 0, 0, 0);
    acc[0][1] = __builtin_amdgcn_mfma_f32_16x16x32_bf16(af0, bf1, acc[0][1], 0, 0, 0);
    acc[1][0] = __builtin_amdgcn_mfma_f32_16x16x32_bf16(af1, bf0, acc[1][0], 0, 0, 0);
    acc[1][1] = __builtin_amdgcn_mfma_f32_16x16x32_bf16(af1, bf1, acc[1][1], 0, 0, 0);
  }
  #pragma unroll
  for (int rt = 0; rt < 2; ++rt) {
    #pragma unroll
    for (int ct = 0; ct < 2; ++ct) {
      int col = colBase + ct * 16 + l16;
      int r0 = rowBase + rt * 16 + quad * 4;
      if (MODE == 0) {
        u16* C = (u16*)Cp;
        #pragma unroll
        for (int r = 0; r < 4; ++r)
          C[(size_t)(r0 + r) * N + col] = f2bf(acc[rt][ct][r] * scale);
      } else if (MODE == 1) {
        // store C^T packed: addr = (b*512 + col)*2048 + (row within batch)
        u16* C = (u16*)Cp;
        int bb = r0 >> 11, ml = r0 & 2047;
        ushort4 o;
        o.x = f2bf(acc[rt][ct][0]); o.y = f2bf(acc[rt][ct][1]);
        o.z = f2bf(acc[rt][ct][2]); o.w = f2bf(acc[rt][ct][3]);
        *(ushort4*)(C + ((size_t)(bb * 512 + col) * 2048 + ml)) = o;
      } else {
        float* C = (float*)Cp;
        float bv = bias ? bias[col] : 0.f;
        #pragma unroll
        for (int r = 0; r < 4; ++r)
          C[(size_t)(r0 + r) * N + col] = acc[rt][ct][r] + bv;
      }
    }
  }
}

// ---------------- flash attention (no-max softmax, barrier-free) --------------
// q: [B,N,H*D] bf16 (pre-scaled by 1/8), k: [B,M,H*D] bf16,
// vT: [(b*512 + h*64 + d), M] bf16, o: [B,N,H*D] bf16
//
// Scores computed TRANSPOSED: S^T = mfma(K_frag, Q_frag) so query = lane&15
// stays fixed; converting exp(S) to the PV A-fragment (key = quad*8+j) is a
// pure key-dim redistribution: 2 shuffles + 1 select per register. No LDS,
// no barriers. Max-subtraction dropped: scores ~N(0,1), |s|max ~ 6 ->
// exp(s) <= ~400, row sums ~3e3 -- safe in fp32.
__global__ __launch_bounds__(256) void attn_kernel(const u16* __restrict__ qb,
    const u16* __restrict__ kb, const u16* __restrict__ vT,
    u16* __restrict__ ob) {
  const int lane = threadIdx.x & 63, wave = threadIdx.x >> 6;
  const int quad = lane >> 4, l16 = lane & 15;
  int bid = blockIdx.x;
  int bh = bid >> 5;          // 32 q-tiles (of 64 rows) per (b,h)
  int qt = bid & 31;
  int b = bh >> 3, h = bh & 7;
  int qrow = qt * 64 + wave * 16;

  const u16* qp = qb + ((size_t)(b * 2048 + qrow + l16) * 512 + h * 64) + quad * 8;
  frag16 qf0 = *(const frag16*)qp;
  frag16 qf1 = *(const frag16*)(qp + 32);

  facc O[4] = {};
  float lsum = 0.f;

  const u16* kbase = kb + ((size_t)(b * 2048 + l16) * 512 + h * 64) + quad * 8;
  const u16* vbase = vT + ((size_t)(b * 512 + h * 64 + l16) * 2048) + quad * 8;

  const int srcq16 = ((quad & 1) * 2) * 16 + l16;   // shuffle base lane
  for (int j0 = 0; j0 < 2048; j0 += 32) {
    const u16* kp = kbase + (size_t)j0 * 512;
    frag16 k00 = *(const frag16*)kp;                  // keys j0..j0+15, d 0..31
    frag16 k01 = *(const frag16*)(kp + 32);           // d 32..63
    frag16 k10 = *(const frag16*)(kp + 16 * 512);     // keys j0+16..j0+31
    frag16 k11 = *(const frag16*)(kp + 16 * 512 + 32);
    facc z = {};
    // S^T: rows (quad*4+r) = key, cols (l16) = query
    facc c0 = __builtin_amdgcn_mfma_f32_16x16x32_bf16(k00, qf0, z, 0, 0, 0);
    c0 = __builtin_amdgcn_mfma_f32_16x16x32_bf16(k01, qf1, c0, 0, 0, 0);
    facc c1 = __builtin_amdgcn_mfma_f32_16x16x32_bf16(k10, qf0, z, 0, 0, 0);
    c1 = __builtin_amdgcn_mfma_f32_16x16x32_bf16(k11, qf1, c1, 0, 0, 0);

    float e0[4], e1[4];
    #pragma unroll
    for (int r = 0; r < 4; ++r) { e0[r] = __expf(c0[r]); e1[r] = __expf(c1[r]); }

    // redistribute: p[j] = exp-score for key j0 + quad*8 + j, query l16
    float p[8];
    #pragma unroll
    for (int j = 0; j < 8; ++j) {
      int srclane = srcq16 + ((j >> 2) * 16);
      float v0 = __shfl(e0[j & 3], srclane);
      float v1 = __shfl(e1[j & 3], srclane);
      p[j] = (quad & 2) ? v1 : v0;
    }
    #pragma unroll
    for (int j = 0; j < 8; ++j) lsum += p[j];

    // pack to bf16 frag (round-half-up via +0x8000 then take hi16)
    union { frag16 f; unsigned u[4]; } pk;
    #pragma unroll
    for (int i = 0; i < 4; ++i)
      pk.u[i] = __builtin_amdgcn_perm(fbits(p[2 * i + 1]) + 0x8000u,
                                      fbits(p[2 * i]) + 0x8000u, 0x07060302u);

    #pragma unroll
    for (int ct = 0; ct < 4; ++ct) {
      frag16 vf = *(const frag16*)(vbase + (size_t)(ct * 16) * 2048 + j0);
      O[ct] = __builtin_amdgcn_mfma_f32_16x16x32_bf16(pk.f, vf, O[ct], 0, 0, 0);
    }
  }

  // reduce lsum across the 4 quads -> every lane holds L[query = l16]
  lsum += __shfl_xor(lsum, 16);
  lsum += __shfl_xor(lsum, 32);
  // epilogue rows are quad*4+r; fetch matching L
  float rinv[4];
  #pragma unroll
  for (int r = 0; r < 4; ++r) rinv[r] = 1.0f / __shfl(lsum, quad * 4 + r);

  #pragma unroll
  for (int ct = 0; ct < 4; ++ct) {
    #pragma unroll
    for (int r = 0; r < 4; ++r) {
      float o = O[ct][r] * rinv[r];
      int row = qrow + quad * 4 + r;
      ob[(size_t)(b * 2048 + row) * 512 + h * 64 + ct * 16 + l16] = f2bf(o);
    }
  }
}

// ---------------- launch ------------------------------------------------------
extern "C" void kernel_launch(void* const* d_in, const int* in_sizes, int n_in,
                              void* d_out, int out_size, void* d_ws, size_t ws_size,
                              hipStream_t stream) {
  const float* x   = (const float*)d_in[0];
  const float* ctx = (const float*)d_in[1];
  const float* Wq  = (const float*)d_in[2];
  const float* Wk  = (const float*)d_in[3];
  const float* Wv  = (const float*)d_in[4];
  const float* W1  = (const float*)d_in[5];
  const float* b1  = (const float*)d_in[6];
  const float* W2  = (const float*)d_in[7];
  const float* b2  = (const float*)d_in[8];
  const float* Wo  = (const float*)d_in[9];
  const float* bo  = (const float*)d_in[10];
  float* out = (float*)d_out;

  char* ws = (char*)d_ws;
  size_t off = 0;
  auto alloc = [&](size_t bytes) {
    char* p = ws + off;
    off += (bytes + 255) & ~(size_t)255;
    return p;
  };
  u16* xb   = (u16*)alloc(8192ull * 512 * 2);
  u16* qb   = (u16*)alloc(8192ull * 512 * 2);
  u16* kb   = (u16*)alloc(8192ull * 512 * 2);
  u16* vT   = (u16*)alloc(8192ull * 512 * 2);
  u16* ob   = (u16*)alloc(8192ull * 512 * 2);
  u16* gctx = (u16*)alloc(8192ull * 64 * 2);
  u16* WqT  = (u16*)alloc(512ull * 512 * 2);
  u16* WkT  = (u16*)alloc(512ull * 64 * 2);
  u16* WvT  = (u16*)alloc(512ull * 64 * 2);
  u16* WoT  = (u16*)alloc(512ull * 512 * 2);

  wtrans_kernel<<<(512 * 512 + 255) / 256, 256, 0, stream>>>(Wq, WqT, 512, 512);
  wtrans_kernel<<<(64 * 512 + 255) / 256, 256, 0, stream>>>(Wk, WkT, 64, 512);
  wtrans_kernel<<<(64 * 512 + 255) / 256, 256, 0, stream>>>(Wv, WvT, 64, 512);
  wtrans_kernel<<<(512 * 512 + 255) / 256, 256, 0, stream>>>(Wo, WoT, 512, 512);
  cvt_kernel<<<(8192 * 512 / 4 + 255) / 256, 256, 0, stream>>>((const float4*)x, xb, 8192 * 512 / 4);
  gate_kernel<<<2048, 256, 0, stream>>>(ctx, W1, b1, W2, b2, gctx);

  // q = x @ Wq, scaled by 1/sqrt(64)
  gemm_bt<0><<<dim3(8, 128), 256, 0, stream>>>(xb, WqT, qb, nullptr, 8192, 512, 512, 0.125f);
  // k = gctx @ Wk
  gemm_bt<0><<<dim3(8, 128), 256, 0, stream>>>(gctx, WkT, kb, nullptr, 8192, 512, 64, 1.f);
  // vT = (gctx @ Wv)^T packed per (b,h,d)
  gemm_bt<1><<<dim3(8, 128), 256, 0, stream>>>(gctx, WvT, vT, nullptr, 8192, 512, 64, 1.f);

  attn_kernel<<<1024, 256, 0, stream>>>(qb, kb, vT, ob);

  // out = ob @ Wo + bo  (fp32)
  gemm_bt<2><<<dim3(8, 128), 256, 0, stream>>>(ob, WoT, out, bo, 8192, 512, 512, 1.f);
}

// Round 5
// 231.229 us; speedup vs baseline: 1.7774x; 1.7672x over previous
//
#include <hip/hip_runtime.h>

typedef unsigned short u16;
using frag16 = __attribute__((ext_vector_type(8))) short;   // 8 x bf16 (4 VGPRs)
using facc   = __attribute__((ext_vector_type(4))) float;   // 4 x fp32 acc
using facc16 = __attribute__((ext_vector_type(16))) float;  // 16 x fp32 acc

#define DEV static __device__ __forceinline__

DEV u16 f2bf(float f) {
  union { float f; unsigned u; } v; v.f = f;
  unsigned r = v.u + 0x7fffu + ((v.u >> 16) & 1u);
  return (u16)(r >> 16);
}
DEV unsigned fbits(float f) {
  union { float f; unsigned u; } v; v.f = f;
  return v.u;
}
// pack two fp32 -> two bf16 (lo in low half), round-half-up
DEV unsigned pkbf(float lo, float hi) {
  return __builtin_amdgcn_perm(fbits(hi) + 0x8000u, fbits(lo) + 0x8000u, 0x07060302u);
}

// ---------------- all four weight transposes in one launch --------------------
__global__ __launch_bounds__(256) void wtrans_all(
    const float* __restrict__ Wq, const float* __restrict__ Wk,
    const float* __restrict__ Wv, const float* __restrict__ Wo,
    u16* __restrict__ WqT, u16* __restrict__ WkT,
    u16* __restrict__ WvT, u16* __restrict__ WoT) {
  int id = blockIdx.x * 256 + threadIdx.x;     // 589824 total
  const float* W; u16* WT; int K, idx;
  if (id < 262144)      { W = Wq; WT = WqT; K = 512; idx = id; }
  else if (id < 294912) { W = Wk; WT = WkT; K = 64;  idx = id - 262144; }
  else if (id < 327680) { W = Wv; WT = WvT; K = 64;  idx = id - 294912; }
  else                  { W = Wo; WT = WoT; K = 512; idx = id - 327680; }
  int n = idx / K, k = idx - n * K;
  WT[idx] = f2bf(W[k * 512 + n]);
}

// ---------------- x fp32 -> bf16 ---------------------------------------------
__global__ void cvt_kernel(const float4* __restrict__ x, u16* __restrict__ xb, int n4) {
  int id = blockIdx.x * 256 + threadIdx.x;
  if (id >= n4) return;
  float4 v = x[id];
  ushort4 o;
  o.x = f2bf(v.x); o.y = f2bf(v.y); o.z = f2bf(v.z); o.w = f2bf(v.w);
  *(ushort4*)(xb + (size_t)id * 4) = o;
}

// ---------------- gate: gctx = bf16(ctx * sigmoid(relu(ctx@W1+b1)@W2+b2)) -----
__global__ __launch_bounds__(256) void gate_kernel(const float* __restrict__ ctx,
    const float* __restrict__ W1, const float* __restrict__ b1,
    const float* __restrict__ W2, const float* __restrict__ b2,
    u16* __restrict__ gctx) {
  int wave = threadIdx.x >> 6, lane = threadIdx.x & 63;
  int row = blockIdx.x * 4 + wave;            // 8192 rows total
  __shared__ float sc[4][64];
  float cv = ctx[(size_t)row * 64 + lane];
  sc[wave][lane] = cv;
  __syncthreads();
  float h = 0.f;
  if (lane < 32) {
    h = b1[lane];
    #pragma unroll
    for (int i = 0; i < 64; ++i) h += sc[wave][i] * W1[i * 32 + lane];
    h = fmaxf(h, 0.f) * W2[lane];
  }
  #pragma unroll
  for (int off = 32; off; off >>= 1) h += __shfl_xor(h, off);
  float g = 1.f / (1.f + __expf(-(h + b2[0])));
  gctx[(size_t)row * 64 + lane] = f2bf(cv * g);
}

// ---------------- generic MFMA GEMM: C[M,N] = A[M,K](bf16) @ BT[N,K](bf16)^T --
// MODE 0: bf16 out, scaled. MODE 2: fp32 out + bias.
// MODE 3: K fragment-packed out (32x32x16 A-operand order, keys as M).
// MODE 4: V fragment-packed out (32x32x16 A-operand order, V^T: dims as M).
template<int MODE>
__global__ __launch_bounds__(256) void gemm_bt(const u16* __restrict__ A,
    const u16* __restrict__ BT, void* __restrict__ Cp,
    const float* __restrict__ bias, int M, int N, int K, float scale) {
  int lane = threadIdx.x & 63, wave = threadIdx.x >> 6;
  int quad = lane >> 4, l16 = lane & 15;
  int wr = wave >> 1, wc = wave & 1;
  int rowBase = blockIdx.y * 64 + wr * 32;
  int colBase = blockIdx.x * 64 + wc * 32;
  facc acc[2][2] = {};
  const u16* a0 = A + (size_t)(rowBase + l16) * K + quad * 8;
  const u16* a1 = a0 + (size_t)16 * K;
  const u16* b0 = BT + (size_t)(colBase + l16) * K + quad * 8;
  const u16* b1p = b0 + (size_t)16 * K;
  for (int kk = 0; kk < K; kk += 32) {
    frag16 af0 = *(const frag16*)(a0 + kk);
    frag16 af1 = *(const frag16*)(a1 + kk);
    frag16 bf0 = *(const frag16*)(b0 + kk);
    frag16 bf1 = *(const frag16*)(b1p + kk);
    acc[0][0] = __builtin_amdgcn_mfma_f32_16x16x32_bf16(af0, bf0, acc[0][0], 0, 0, 0);
    acc[0][1] = __builtin_amdgcn_mfma_f32_16x16x32_bf16(af0, bf1, acc[0][1], 0, 0, 0);
    acc[1][0] = __builtin_amdgcn_mfma_f32_16x16x32_bf16(af1, bf0, acc[1][0], 0, 0, 0);
    acc[1][1] = __builtin_amdgcn_mfma_f32_16x16x32_bf16(af1, bf1, acc[1][1], 0, 0, 0);
  }
  #pragma unroll
  for (int rt = 0; rt < 2; ++rt) {
    #pragma unroll
    for (int ct = 0; ct < 2; ++ct) {
      int col = colBase + ct * 16 + l16;
      int r0g = rowBase + rt * 16 + quad * 4;
      if (MODE == 0) {
        u16* C = (u16*)Cp;
        #pragma unroll
        for (int r = 0; r < 4; ++r)
          C[(size_t)(r0g + r) * N + col] = f2bf(acc[rt][ct][r] * scale);
      } else if (MODE == 2) {
        float* C = (float*)Cp;
        float bv = bias ? bias[col] : 0.f;
        #pragma unroll
        for (int r = 0; r < 4; ++r)
          C[(size_t)(r0g + r) * N + col] = acc[rt][ct][r] + bv;
      } else if (MODE == 3) {
        // K-pack: rows are keys m, col -> (h,d). frag lane = ((d>>3)&1)*32+(m&31)
        u16* C = (u16*)Cp;
        int hh = col >> 6, d = col & 63;
        int b = r0g >> 11;
        #pragma unroll
        for (int r = 0; r < 4; ++r) {
          int m = (r0g + r) & 2047;
          size_t addr = ((((size_t)(b * 8 + hh) * 64 + (m >> 5)) * 4 + (d >> 4)) * 64
                         + ((d >> 3) & 1) * 32 + (m & 31)) * 8 + (d & 7);
          C[addr] = f2bf(acc[rt][ct][r]);
        }
      } else {
        // V-pack (V^T): rows are keys m (4 consecutive -> ushort4), col -> (h,d)
        u16* C = (u16*)Cp;
        int hh = col >> 6, d = col & 63;
        int b = r0g >> 11;
        int m = r0g & 2047;
        size_t addr = ((((size_t)(b * 8 + hh) * 64 + (m >> 5)) * 4
                        + ((m >> 4) & 1) * 2 + (d >> 5)) * 64
                       + ((m >> 3) & 1) * 32 + (d & 31)) * 8 + (m & 7);
        ushort4 o;
        o.x = f2bf(acc[rt][ct][0]); o.y = f2bf(acc[rt][ct][1]);
        o.z = f2bf(acc[rt][ct][2]); o.w = f2bf(acc[rt][ct][3]);
        *(ushort4*)(C + addr) = o;
      }
    }
  }
}

// ---------------- flash attention, 32x32 MFMA, packed K/V, key-split ----------
// qb: [B,N,512] bf16 pre-scaled by 0.125*log2(e). Kp/Vp: fragment-packed.
// Opart: [2][8192][512] fp32, Lpart: [2][8192*8] fp32 (per row PER HEAD).
// Block decode puts bh in low 5 bits so same-(b,h) blocks share an XCD (L2 reuse).
__global__ __launch_bounds__(256, 3) void attn_kernel(
    const u16* __restrict__ qb, const u16* __restrict__ Kp,
    const u16* __restrict__ Vp, float* __restrict__ Opart,
    float* __restrict__ Lpart) {
  const int lane = threadIdx.x & 63, wave = threadIdx.x >> 6;
  const int l32 = lane & 31;
  const int hi = lane >> 5;           // half-wave index
  const int bid = blockIdx.x;
  const int bh = bid & 31;            // low bits -> XCD locality
  const int qblk = (bid >> 5) & 15;
  const int js = bid >> 9;
  const int b = bh >> 3, h = bh & 7;
  const int q0 = (qblk * 4 + wave) * 32;
  const int rowg = b * 2048 + q0 + l32;

  // Q B-operand frags: n=q=l32, k=d = c*16 + hi*8 + jj
  const u16* qp = qb + (size_t)rowg * 512 + h * 64 + hi * 8;
  frag16 qf0 = *(const frag16*)(qp);
  frag16 qf1 = *(const frag16*)(qp + 16);
  frag16 qf2 = *(const frag16*)(qp + 32);
  frag16 qf3 = *(const frag16*)(qp + 48);

  facc16 O0 = {}, O1 = {};
  float lsum = 0.f;

  const size_t ts = 2048;  // u16 per 32-key tile (4 frags x 64 lanes x 8)
  const u16* kpb = Kp + (size_t)(bh * 64 + js * 32) * ts + lane * 8;
  const u16* vpb = Vp + (size_t)(bh * 64 + js * 32) * ts + lane * 8;

  for (int t = 0; t < 32; ++t) {
    const u16* kt = kpb + (size_t)t * ts;
    frag16 kf0 = *(const frag16*)(kt);
    frag16 kf1 = *(const frag16*)(kt + 512);
    frag16 kf2 = *(const frag16*)(kt + 1024);
    frag16 kf3 = *(const frag16*)(kt + 1536);
    const u16* vt = vpb + (size_t)t * ts;
    frag16 vf00 = *(const frag16*)(vt);           // keys 0-15, d 0-31
    frag16 vf01 = *(const frag16*)(vt + 512);     // keys 0-15, d 32-63
    frag16 vf10 = *(const frag16*)(vt + 1024);    // keys 16-31, d 0-31
    frag16 vf11 = *(const frag16*)(vt + 1536);    // keys 16-31, d 32-63

    facc16 S = {};
    S = __builtin_amdgcn_mfma_f32_32x32x16_bf16(kf0, qf0, S, 0, 0, 0);
    S = __builtin_amdgcn_mfma_f32_32x32x16_bf16(kf1, qf1, S, 0, 0, 0);
    S = __builtin_amdgcn_mfma_f32_32x32x16_bf16(kf2, qf2, S, 0, 0, 0);
    S = __builtin_amdgcn_mfma_f32_32x32x16_bf16(kf3, qf3, S, 0, 0, 0);

    float e[16];
    #pragma unroll
    for (int r = 0; r < 16; ++r) e[r] = __builtin_amdgcn_exp2f(S[r]);
    #pragma unroll
    for (int r = 0; r < 16; ++r) lsum += e[r];

    // S^T C-layout -> P B-operand layout: half-wave swap of 4 regs per chunk
    unsigned pu[2][4];
    #pragma unroll
    for (int c = 0; c < 2; ++c) {
      const float* ee = e + c * 8;
      float y0 = hi ? ee[0] : ee[4];
      float y1 = hi ? ee[1] : ee[5];
      float y2 = hi ? ee[2] : ee[6];
      float y3 = hi ? ee[3] : ee[7];
      float x0 = __shfl_xor(y0, 32);
      float x1 = __shfl_xor(y1, 32);
      float x2 = __shfl_xor(y2, 32);
      float x3 = __shfl_xor(y3, 32);
      unsigned pA0 = pkbf(ee[0], ee[1]), pA1 = pkbf(ee[2], ee[3]);
      unsigned pB0 = pkbf(ee[4], ee[5]), pB1 = pkbf(ee[6], ee[7]);
      unsigned pX0 = pkbf(x0, x1), pX1 = pkbf(x2, x3);
      pu[c][0] = hi ? pX0 : pA0;
      pu[c][1] = hi ? pX1 : pA1;
      pu[c][2] = hi ? pB0 : pX0;
      pu[c][3] = hi ? pB1 : pX1;
    }
    frag16 P0 = *(frag16*)&pu[0][0];
    frag16 P1 = *(frag16*)&pu[1][0];

    O0 = __builtin_amdgcn_mfma_f32_32x32x16_bf16(vf00, P0, O0, 0, 0, 0);
    O0 = __builtin_amdgcn_mfma_f32_32x32x16_bf16(vf10, P1, O0, 0, 0, 0);
    O1 = __builtin_amdgcn_mfma_f32_32x32x16_bf16(vf01, P0, O1, 0, 0, 0);
    O1 = __builtin_amdgcn_mfma_f32_32x32x16_bf16(vf11, P1, O1, 0, 0, 0);
  }

  lsum += __shfl_xor(lsum, 32);

  // O^T C-layout: col=q=l32, row=d = dt*32 + 8*(reg>>2) + 4*hi + (reg&3)
  float* op = Opart + ((size_t)js * 8192 + rowg) * 512 + h * 64;
  #pragma unroll
  for (int dt = 0; dt < 2; ++dt) {
    #pragma unroll
    for (int rq = 0; rq < 4; ++rq) {
      float4 v;
      if (dt == 0) { v.x = O0[rq*4]; v.y = O0[rq*4+1]; v.z = O0[rq*4+2]; v.w = O0[rq*4+3]; }
      else         { v.x = O1[rq*4]; v.y = O1[rq*4+1]; v.z = O1[rq*4+2]; v.w = O1[rq*4+3]; }
      int d0 = dt * 32 + 8 * rq + 4 * hi;
      *(float4*)(op + d0) = v;
    }
  }
  // L is per (row, head)!  [2][8192*8]
  if (!hi) Lpart[(size_t)js * 65536 + (size_t)rowg * 8 + h] = lsum;
}

// ---------------- combine the two key-split partials -> bf16 ------------------
__global__ __launch_bounds__(256) void combine_kernel(const float* __restrict__ Opart,
    const float* __restrict__ Lpart, u16* __restrict__ ob) {
  int id = blockIdx.x * 256 + threadIdx.x;   // 8192*128
  int row = id >> 7, c4 = (id & 127) * 4;
  int hh = c4 >> 6;
  size_t o = (size_t)row * 512 + c4;
  const float4 o0 = *(const float4*)(Opart + o);
  const float4 o1 = *(const float4*)(Opart + (size_t)8192 * 512 + o);
  float rl = 1.f / (Lpart[(size_t)row * 8 + hh] + Lpart[65536 + (size_t)row * 8 + hh]);
  ushort4 u;
  u.x = f2bf((o0.x + o1.x) * rl);
  u.y = f2bf((o0.y + o1.y) * rl);
  u.z = f2bf((o0.z + o1.z) * rl);
  u.w = f2bf((o0.w + o1.w) * rl);
  *(ushort4*)(ob + o) = u;
}

// ---------------- launch ------------------------------------------------------
extern "C" void kernel_launch(void* const* d_in, const int* in_sizes, int n_in,
                              void* d_out, int out_size, void* d_ws, size_t ws_size,
                              hipStream_t stream) {
  const float* x   = (const float*)d_in[0];
  const float* ctx = (const float*)d_in[1];
  const float* Wq  = (const float*)d_in[2];
  const float* Wk  = (const float*)d_in[3];
  const float* Wv  = (const float*)d_in[4];
  const float* W1  = (const float*)d_in[5];
  const float* b1  = (const float*)d_in[6];
  const float* W2  = (const float*)d_in[7];
  const float* b2  = (const float*)d_in[8];
  const float* Wo  = (const float*)d_in[9];
  const float* bo  = (const float*)d_in[10];
  float* out = (float*)d_out;

  char* ws = (char*)d_ws;
  size_t off = 0;
  auto alloc = [&](size_t bytes) {
    char* p = ws + off;
    off += (bytes + 255) & ~(size_t)255;
    return p;
  };
  u16* xb    = (u16*)alloc(8192ull * 512 * 2);
  u16* qb    = (u16*)alloc(8192ull * 512 * 2);
  u16* Kp    = (u16*)alloc(8192ull * 512 * 2);
  u16* Vp    = (u16*)alloc(8192ull * 512 * 2);
  u16* ob    = (u16*)alloc(8192ull * 512 * 2);
  u16* gctx  = (u16*)alloc(8192ull * 64 * 2);
  u16* WqT   = (u16*)alloc(512ull * 512 * 2);
  u16* WkT   = (u16*)alloc(512ull * 64 * 2);
  u16* WvT   = (u16*)alloc(512ull * 64 * 2);
  u16* WoT   = (u16*)alloc(512ull * 512 * 2);
  float* Opart = (float*)alloc(2ull * 8192 * 512 * 4);
  float* Lpart = (float*)alloc(2ull * 65536 * 4);

  wtrans_all<<<2304, 256, 0, stream>>>(Wq, Wk, Wv, Wo, WqT, WkT, WvT, WoT);
  cvt_kernel<<<4096, 256, 0, stream>>>((const float4*)x, xb, 8192 * 512 / 4);
  gate_kernel<<<2048, 256, 0, stream>>>(ctx, W1, b1, W2, b2, gctx);

  // q = x @ Wq, scaled by (1/sqrt(64)) * log2(e) for exp2-softmax
  gemm_bt<0><<<dim3(8, 128), 256, 0, stream>>>(xb, WqT, qb, nullptr, 8192, 512, 512,
                                               0.125f * 1.4426950408889634f);
  // k = gctx @ Wk  -> fragment-packed
  gemm_bt<3><<<dim3(8, 128), 256, 0, stream>>>(gctx, WkT, Kp, nullptr, 8192, 512, 64, 1.f);
  // v = gctx @ Wv  -> fragment-packed (V^T)
  gemm_bt<4><<<dim3(8, 128), 256, 0, stream>>>(gctx, WvT, Vp, nullptr, 8192, 512, 64, 1.f);

  attn_kernel<<<1024, 256, 0, stream>>>(qb, Kp, Vp, Opart, Lpart);
  combine_kernel<<<4096, 256, 0, stream>>>(Opart, Lpart, ob);

  // out = ob @ Wo + bo  (fp32)
  gemm_bt<2><<<dim3(8, 128), 256, 0, stream>>>(ob, WoT, out, bo, 8192, 512, 512, 1.f);
}

// Round 6
// 197.838 us; speedup vs baseline: 2.0774x; 1.1688x over previous
//
#include <hip/hip_runtime.h>

typedef unsigned short u16;
typedef unsigned int u32;
using frag16 = __attribute__((ext_vector_type(8))) short;   // 8 x bf16 (4 VGPRs)
using facc   = __attribute__((ext_vector_type(4))) float;   // 4 x fp32 acc
using facc16 = __attribute__((ext_vector_type(16))) float;  // 16 x fp32 acc

#define DEV static __device__ __forceinline__

DEV u16 f2bf(float f) {
  union { float f; unsigned u; } v; v.f = f;
  unsigned r = v.u + 0x7fffu + ((v.u >> 16) & 1u);
  return (u16)(r >> 16);
}
DEV unsigned fbits(float f) {
  union { float f; unsigned u; } v; v.f = f;
  return v.u;
}
// pack two fp32 -> two bf16 (lo in low half), round-half-up
DEV unsigned pkbf(float lo, float hi) {
  return __builtin_amdgcn_perm(fbits(hi) + 0x8000u, fbits(lo) + 0x8000u, 0x07060302u);
}
// async global->LDS, 16B per lane. LDS dest = wave-uniform base + lane*16.
DEV void gld16(const u16* g, u16* l) {
  __builtin_amdgcn_global_load_lds(
      (__attribute__((address_space(1))) unsigned int*)(g),
      (__attribute__((address_space(3))) unsigned int*)(l), 16, 0, 0);
}

// ---------------- all four weight transposes in one launch --------------------
__global__ __launch_bounds__(256) void wtrans_all(
    const float* __restrict__ Wq, const float* __restrict__ Wk,
    const float* __restrict__ Wv, const float* __restrict__ Wo,
    u16* __restrict__ WqT, u16* __restrict__ WkT,
    u16* __restrict__ WvT, u16* __restrict__ WoT) {
  int id = blockIdx.x * 256 + threadIdx.x;     // 589824 total
  const float* W; u16* WT; int K, idx;
  if (id < 262144)      { W = Wq; WT = WqT; K = 512; idx = id; }
  else if (id < 294912) { W = Wk; WT = WkT; K = 64;  idx = id - 262144; }
  else if (id < 327680) { W = Wv; WT = WvT; K = 64;  idx = id - 294912; }
  else                  { W = Wo; WT = WoT; K = 512; idx = id - 327680; }
  int n = idx / K, k = idx - n * K;
  WT[idx] = f2bf(W[k * 512 + n]);
}

// ---------------- x fp32 -> bf16 ---------------------------------------------
__global__ void cvt_kernel(const float4* __restrict__ x, u16* __restrict__ xb, int n4) {
  int id = blockIdx.x * 256 + threadIdx.x;
  if (id >= n4) return;
  float4 v = x[id];
  ushort4 o;
  o.x = f2bf(v.x); o.y = f2bf(v.y); o.z = f2bf(v.z); o.w = f2bf(v.w);
  *(ushort4*)(xb + (size_t)id * 4) = o;
}

// ---------------- gate: gctx = bf16(ctx * sigmoid(relu(ctx@W1+b1)@W2+b2)) -----
__global__ __launch_bounds__(256) void gate_kernel(const float* __restrict__ ctx,
    const float* __restrict__ W1, const float* __restrict__ b1,
    const float* __restrict__ W2, const float* __restrict__ b2,
    u16* __restrict__ gctx) {
  int wave = threadIdx.x >> 6, lane = threadIdx.x & 63;
  int row = blockIdx.x * 4 + wave;            // 8192 rows total
  __shared__ float sc[4][64];
  float cv = ctx[(size_t)row * 64 + lane];
  sc[wave][lane] = cv;
  __syncthreads();
  float h = 0.f;
  if (lane < 32) {
    h = b1[lane];
    #pragma unroll
    for (int i = 0; i < 64; ++i) h += sc[wave][i] * W1[i * 32 + lane];
    h = fmaxf(h, 0.f) * W2[lane];
  }
  #pragma unroll
  for (int off = 32; off; off >>= 1) h += __shfl_xor(h, off);
  float g = 1.f / (1.f + __expf(-(h + b2[0])));
  gctx[(size_t)row * 64 + lane] = f2bf(cv * g);
}

// ---------------- big GEMM, m97-style: 128x64 tile, BK=32, global_load_lds ----
// C[M,N] = A[M,K] @ BT[N,K]^T, K=512. grid (N/64, M/128), 256 threads.
// MODE 0: bf16 out * scale. MODE 2: fp32 out + bias.
template<int MODE>
__global__ __launch_bounds__(256) void gemm128(const u16* __restrict__ A,
    const u16* __restrict__ BT, void* __restrict__ Cp,
    const float* __restrict__ bias, int N, float scale) {
  const int K = 512;
  const int lane = threadIdx.x & 63, wave = threadIdx.x >> 6;
  const int quad = lane >> 4, l16 = lane & 15;
  const int wr = wave >> 1, wc = wave & 1;
  const int m0 = blockIdx.y * 128, n0 = blockIdx.x * 64;

  __shared__ __align__(16) u16 As[128 * 32];   // [row][k] 32 k per row
  __shared__ __align__(16) u16 Bs[64 * 32];

  // staging source pointers (per-lane)
  const u16* gA = A + (size_t)(m0 + wave * 32 + (lane >> 2)) * K + (lane & 3) * 8;
  const u16* gB = BT + (size_t)(n0 + wave * 16 + (lane >> 2)) * K + (lane & 3) * 8;
  // staging LDS dests (wave-uniform)
  u16* lA0 = As + wave * 1024;            // rows wave*32 .. +15
  u16* lA1 = As + wave * 1024 + 512;      // rows wave*32+16 .. +31
  u16* lB  = Bs + wave * 512;             // rows wave*16 .. +15

  facc acc[4][2] = {};

  for (int k0 = 0; k0 < K; k0 += 32) {
    if (k0) __syncthreads();
    gld16(gA + k0, lA0);
    gld16(gA + 16 * K + k0, lA1);
    gld16(gB + k0, lB);
    __syncthreads();

    frag16 af[4], bf[2];
    #pragma unroll
    for (int rt = 0; rt < 4; ++rt)
      af[rt] = *(const frag16*)(As + (wr * 64 + rt * 16 + l16) * 32 + quad * 8);
    #pragma unroll
    for (int ct = 0; ct < 2; ++ct)
      bf[ct] = *(const frag16*)(Bs + (wc * 32 + ct * 16 + l16) * 32 + quad * 8);
    #pragma unroll
    for (int rt = 0; rt < 4; ++rt)
      #pragma unroll
      for (int ct = 0; ct < 2; ++ct)
        acc[rt][ct] = __builtin_amdgcn_mfma_f32_16x16x32_bf16(af[rt], bf[ct], acc[rt][ct], 0, 0, 0);
  }

  #pragma unroll
  for (int rt = 0; rt < 4; ++rt) {
    #pragma unroll
    for (int ct = 0; ct < 2; ++ct) {
      int col = n0 + wc * 32 + ct * 16 + l16;
      int r0g = m0 + wr * 64 + rt * 16 + quad * 4;
      if (MODE == 0) {
        u16* C = (u16*)Cp;
        #pragma unroll
        for (int r = 0; r < 4; ++r)
          C[(size_t)(r0g + r) * N + col] = f2bf(acc[rt][ct][r] * scale);
      } else {
        float* C = (float*)Cp;
        float bv = bias[col];
        #pragma unroll
        for (int r = 0; r < 4; ++r)
          C[(size_t)(r0g + r) * N + col] = acc[rt][ct][r] + bv;
      }
    }
  }
}

// ---------------- k/v projection GEMM (K=64) with fragment-packed epilogues ---
// MODE 3: K fragment-packed out (32x32x16 A-operand order, keys as M).
// MODE 4: V fragment-packed out (32x32x16 A-operand order, V^T: dims as M).
template<int MODE>
__global__ __launch_bounds__(256) void gemm_bt(const u16* __restrict__ A,
    const u16* __restrict__ BT, void* __restrict__ Cp, int M, int N, int K) {
  int lane = threadIdx.x & 63, wave = threadIdx.x >> 6;
  int quad = lane >> 4, l16 = lane & 15;
  int wr = wave >> 1, wc = wave & 1;
  int rowBase = blockIdx.y * 64 + wr * 32;
  int colBase = blockIdx.x * 64 + wc * 32;
  facc acc[2][2] = {};
  const u16* a0 = A + (size_t)(rowBase + l16) * K + quad * 8;
  const u16* a1 = a0 + (size_t)16 * K;
  const u16* b0 = BT + (size_t)(colBase + l16) * K + quad * 8;
  const u16* b1p = b0 + (size_t)16 * K;
  for (int kk = 0; kk < K; kk += 32) {
    frag16 af0 = *(const frag16*)(a0 + kk);
    frag16 af1 = *(const frag16*)(a1 + kk);
    frag16 bf0 = *(const frag16*)(b0 + kk);
    frag16 bf1 = *(const frag16*)(b1p + kk);
    acc[0][0] = __builtin_amdgcn_mfma_f32_16x16x32_bf16(af0, bf0, acc[0][0], 0, 0, 0);
    acc[0][1] = __builtin_amdgcn_mfma_f32_16x16x32_bf16(af0, bf1, acc[0][1], 0, 0, 0);
    acc[1][0] = __builtin_amdgcn_mfma_f32_16x16x32_bf16(af1, bf0, acc[1][0], 0, 0, 0);
    acc[1][1] = __builtin_amdgcn_mfma_f32_16x16x32_bf16(af1, bf1, acc[1][1], 0, 0, 0);
  }
  #pragma unroll
  for (int rt = 0; rt < 2; ++rt) {
    #pragma unroll
    for (int ct = 0; ct < 2; ++ct) {
      int col = colBase + ct * 16 + l16;
      int r0g = rowBase + rt * 16 + quad * 4;
      if (MODE == 3) {
        // K-pack: rows are keys m, col -> (h,d). frag lane = ((d>>3)&1)*32+(m&31)
        u16* C = (u16*)Cp;
        int hh = col >> 6, d = col & 63;
        int b = r0g >> 11;
        #pragma unroll
        for (int r = 0; r < 4; ++r) {
          int m = (r0g + r) & 2047;
          size_t addr = ((((size_t)(b * 8 + hh) * 64 + (m >> 5)) * 4 + (d >> 4)) * 64
                         + ((d >> 3) & 1) * 32 + (m & 31)) * 8 + (d & 7);
          C[addr] = f2bf(acc[rt][ct][r]);
        }
      } else {
        // V-pack (V^T): rows are keys m (4 consecutive -> ushort4), col -> (h,d)
        u16* C = (u16*)Cp;
        int hh = col >> 6, d = col & 63;
        int b = r0g >> 11;
        int m = r0g & 2047;
        size_t addr = ((((size_t)(b * 8 + hh) * 64 + (m >> 5)) * 4
                        + ((m >> 4) & 1) * 2 + (d >> 5)) * 64
                       + ((m >> 3) & 1) * 32 + (d & 31)) * 8 + (m & 7);
        ushort4 o;
        o.x = f2bf(acc[rt][ct][0]); o.y = f2bf(acc[rt][ct][1]);
        o.z = f2bf(acc[rt][ct][2]); o.w = f2bf(acc[rt][ct][3]);
        *(ushort4*)(C + addr) = o;
      }
    }
  }
}

// ---------------- flash attention, 32x32 MFMA, packed K/V, key-split ----------
// qb: [B,N,512] bf16 pre-scaled by 0.125*log2(e). Kp/Vp: fragment-packed.
// Opart: [2][8192][512] fp32, Lpart: [2][8192*8] fp32 (per row PER HEAD).
__global__ __launch_bounds__(256, 3) void attn_kernel(
    const u16* __restrict__ qb, const u16* __restrict__ Kp,
    const u16* __restrict__ Vp, float* __restrict__ Opart,
    float* __restrict__ Lpart) {
  const int lane = threadIdx.x & 63, wave = threadIdx.x >> 6;
  const int l32 = lane & 31;
  const int hi = lane >> 5;           // half-wave index
  const int bid = blockIdx.x;
  const int bh = bid & 31;            // low bits -> XCD locality
  const int qblk = (bid >> 5) & 15;
  const int js = bid >> 9;
  const int b = bh >> 3, h = bh & 7;
  const int q0 = (qblk * 4 + wave) * 32;
  const int rowg = b * 2048 + q0 + l32;

  // Q B-operand frags: n=q=l32, k=d = c*16 + hi*8 + jj
  const u16* qp = qb + (size_t)rowg * 512 + h * 64 + hi * 8;
  frag16 qf0 = *(const frag16*)(qp);
  frag16 qf1 = *(const frag16*)(qp + 16);
  frag16 qf2 = *(const frag16*)(qp + 32);
  frag16 qf3 = *(const frag16*)(qp + 48);

  facc16 O0 = {}, O1 = {};
  float lsum = 0.f;

  const size_t ts = 2048;  // u16 per 32-key tile (4 frags x 64 lanes x 8)
  const u16* kpb = Kp + (size_t)(bh * 64 + js * 32) * ts + lane * 8;
  const u16* vpb = Vp + (size_t)(bh * 64 + js * 32) * ts + lane * 8;

  for (int t = 0; t < 32; ++t) {
    const u16* kt = kpb + (size_t)t * ts;
    frag16 kf0 = *(const frag16*)(kt);
    frag16 kf1 = *(const frag16*)(kt + 512);
    frag16 kf2 = *(const frag16*)(kt + 1024);
    frag16 kf3 = *(const frag16*)(kt + 1536);
    const u16* vt = vpb + (size_t)t * ts;
    frag16 vf00 = *(const frag16*)(vt);           // keys 0-15, d 0-31
    frag16 vf01 = *(const frag16*)(vt + 512);     // keys 0-15, d 32-63
    frag16 vf10 = *(const frag16*)(vt + 1024);    // keys 16-31, d 0-31
    frag16 vf11 = *(const frag16*)(vt + 1536);    // keys 16-31, d 32-63

    facc16 S = {};
    S = __builtin_amdgcn_mfma_f32_32x32x16_bf16(kf0, qf0, S, 0, 0, 0);
    S = __builtin_amdgcn_mfma_f32_32x32x16_bf16(kf1, qf1, S, 0, 0, 0);
    S = __builtin_amdgcn_mfma_f32_32x32x16_bf16(kf2, qf2, S, 0, 0, 0);
    S = __builtin_amdgcn_mfma_f32_32x32x16_bf16(kf3, qf3, S, 0, 0, 0);

    float e[16];
    #pragma unroll
    for (int r = 0; r < 16; ++r) e[r] = __builtin_amdgcn_exp2f(S[r]);
    #pragma unroll
    for (int r = 0; r < 16; ++r) lsum += e[r];

    // S^T C-layout -> P B-operand layout.
    // Pack own e[] first, then select/shuffle packed dwords (half-wave swap).
    unsigned pu[2][4];
    #pragma unroll
    for (int c = 0; c < 2; ++c) {
      const float* ee = e + c * 8;
      unsigned L0 = pkbf(ee[0], ee[1]);
      unsigned L1 = pkbf(ee[2], ee[3]);
      unsigned H0 = pkbf(ee[4], ee[5]);
      unsigned H1 = pkbf(ee[6], ee[7]);
      unsigned Y0 = hi ? L0 : H0;
      unsigned Y1 = hi ? L1 : H1;
      unsigned X0 = (unsigned)__shfl_xor((int)Y0, 32);
      unsigned X1 = (unsigned)__shfl_xor((int)Y1, 32);
      pu[c][0] = hi ? X0 : L0;
      pu[c][1] = hi ? X1 : L1;
      pu[c][2] = hi ? H0 : X0;
      pu[c][3] = hi ? H1 : X1;
    }
    frag16 P0 = *(frag16*)&pu[0][0];
    frag16 P1 = *(frag16*)&pu[1][0];

    O0 = __builtin_amdgcn_mfma_f32_32x32x16_bf16(vf00, P0, O0, 0, 0, 0);
    O0 = __builtin_amdgcn_mfma_f32_32x32x16_bf16(vf10, P1, O0, 0, 0, 0);
    O1 = __builtin_amdgcn_mfma_f32_32x32x16_bf16(vf01, P0, O1, 0, 0, 0);
    O1 = __builtin_amdgcn_mfma_f32_32x32x16_bf16(vf11, P1, O1, 0, 0, 0);
  }

  lsum += __shfl_xor(lsum, 32);

  // O^T C-layout: col=q=l32, row=d = dt*32 + 8*(reg>>2) + 4*hi + (reg&3)
  float* op = Opart + ((size_t)js * 8192 + rowg) * 512 + h * 64;
  #pragma unroll
  for (int dt = 0; dt < 2; ++dt) {
    #pragma unroll
    for (int rq = 0; rq < 4; ++rq) {
      float4 v;
      if (dt == 0) { v.x = O0[rq*4]; v.y = O0[rq*4+1]; v.z = O0[rq*4+2]; v.w = O0[rq*4+3]; }
      else         { v.x = O1[rq*4]; v.y = O1[rq*4+1]; v.z = O1[rq*4+2]; v.w = O1[rq*4+3]; }
      int d0 = dt * 32 + 8 * rq + 4 * hi;
      *(float4*)(op + d0) = v;
    }
  }
  // L is per (row, head): [2][8192*8]
  if (!hi) Lpart[(size_t)js * 65536 + (size_t)rowg * 8 + h] = lsum;
}

// ---------------- combine the two key-split partials -> bf16 ------------------
__global__ __launch_bounds__(256) void combine_kernel(const float* __restrict__ Opart,
    const float* __restrict__ Lpart, u16* __restrict__ ob) {
  int id = blockIdx.x * 256 + threadIdx.x;   // 8192*128
  int row = id >> 7, c4 = (id & 127) * 4;
  int hh = c4 >> 6;
  size_t o = (size_t)row * 512 + c4;
  const float4 o0 = *(const float4*)(Opart + o);
  const float4 o1 = *(const float4*)(Opart + (size_t)8192 * 512 + o);
  float rl = 1.f / (Lpart[(size_t)row * 8 + hh] + Lpart[65536 + (size_t)row * 8 + hh]);
  ushort4 u;
  u.x = f2bf((o0.x + o1.x) * rl);
  u.y = f2bf((o0.y + o1.y) * rl);
  u.z = f2bf((o0.z + o1.z) * rl);
  u.w = f2bf((o0.w + o1.w) * rl);
  *(ushort4*)(ob + o) = u;
}

// ---------------- launch ------------------------------------------------------
extern "C" void kernel_launch(void* const* d_in, const int* in_sizes, int n_in,
                              void* d_out, int out_size, void* d_ws, size_t ws_size,
                              hipStream_t stream) {
  const float* x   = (const float*)d_in[0];
  const float* ctx = (const float*)d_in[1];
  const float* Wq  = (const float*)d_in[2];
  const float* Wk  = (const float*)d_in[3];
  const float* Wv  = (const float*)d_in[4];
  const float* W1  = (const float*)d_in[5];
  const float* b1  = (const float*)d_in[6];
  const float* W2  = (const float*)d_in[7];
  const float* b2  = (const float*)d_in[8];
  const float* Wo  = (const float*)d_in[9];
  const float* bo  = (const float*)d_in[10];
  float* out = (float*)d_out;

  char* ws = (char*)d_ws;
  size_t off = 0;
  auto alloc = [&](size_t bytes) {
    char* p = ws + off;
    off += (bytes + 255) & ~(size_t)255;
    return p;
  };
  u16* xb    = (u16*)alloc(8192ull * 512 * 2);
  u16* qb    = (u16*)alloc(8192ull * 512 * 2);
  u16* Kp    = (u16*)alloc(8192ull * 512 * 2);
  u16* Vp    = (u16*)alloc(8192ull * 512 * 2);
  u16* ob    = (u16*)alloc(8192ull * 512 * 2);
  u16* gctx  = (u16*)alloc(8192ull * 64 * 2);
  u16* WqT   = (u16*)alloc(512ull * 512 * 2);
  u16* WkT   = (u16*)alloc(512ull * 64 * 2);
  u16* WvT   = (u16*)alloc(512ull * 64 * 2);
  u16* WoT   = (u16*)alloc(512ull * 512 * 2);
  float* Opart = (float*)alloc(2ull * 8192 * 512 * 4);
  float* Lpart = (float*)alloc(2ull * 65536 * 4);

  wtrans_all<<<2304, 256, 0, stream>>>(Wq, Wk, Wv, Wo, WqT, WkT, WvT, WoT);
  cvt_kernel<<<4096, 256, 0, stream>>>((const float4*)x, xb, 8192 * 512 / 4);
  gate_kernel<<<2048, 256, 0, stream>>>(ctx, W1, b1, W2, b2, gctx);

  // q = x @ Wq, scaled by (1/sqrt(64)) * log2(e) for exp2-softmax
  gemm128<0><<<dim3(8, 64), 256, 0, stream>>>(xb, WqT, qb, nullptr, 512,
                                              0.125f * 1.4426950408889634f);
  // k = gctx @ Wk  -> fragment-packed
  gemm_bt<3><<<dim3(8, 128), 256, 0, stream>>>(gctx, WkT, Kp, 8192, 512, 64);
  // v = gctx @ Wv  -> fragment-packed (V^T)
  gemm_bt<4><<<dim3(8, 128), 256, 0, stream>>>(gctx, WvT, Vp, 8192, 512, 64);

  attn_kernel<<<1024, 256, 0, stream>>>(qb, Kp, Vp, Opart, Lpart);
  combine_kernel<<<4096, 256, 0, stream>>>(Opart, Lpart, ob);

  // out = ob @ Wo + bo  (fp32)
  gemm128<2><<<dim3(8, 64), 256, 0, stream>>>(ob, WoT, out, bo, 512, 1.f);
}

// Round 7
// 186.694 us; speedup vs baseline: 2.2014x; 1.0597x over previous
//
#include <hip/hip_runtime.h>

typedef unsigned short u16;
typedef unsigned int u32;
using frag16 = __attribute__((ext_vector_type(8))) short;   // 8 x bf16 (4 VGPRs)
using facc   = __attribute__((ext_vector_type(4))) float;   // 4 x fp32 acc
using facc16 = __attribute__((ext_vector_type(16))) float;  // 16 x fp32 acc

#define DEV static __device__ __forceinline__

DEV u16 f2bf(float f) {
  union { float f; unsigned u; } v; v.f = f;
  unsigned r = v.u + 0x7fffu + ((v.u >> 16) & 1u);
  return (u16)(r >> 16);
}
DEV unsigned fbits(float f) {
  union { float f; unsigned u; } v; v.f = f;
  return v.u;
}
// pack two fp32 -> two bf16 (lo in low half), round-half-up
DEV unsigned pkbf(float lo, float hi) {
  return __builtin_amdgcn_perm(fbits(hi) + 0x8000u, fbits(lo) + 0x8000u, 0x07060302u);
}
// async global->LDS, 16B per lane. LDS dest = wave-uniform base + lane*16.
DEV void gld16(const u16* g, u16* l) {
  __builtin_amdgcn_global_load_lds(
      (__attribute__((address_space(1))) unsigned int*)(g),
      (__attribute__((address_space(3))) unsigned int*)(l), 16, 0, 0);
}

// ---------------- prep: x fp32->bf16 (blocks 0..4095) + weight transposes ----
__global__ __launch_bounds__(256) void prep_kernel(const float4* __restrict__ x,
    const float* __restrict__ Wq, const float* __restrict__ Wk,
    const float* __restrict__ Wv, const float* __restrict__ Wo,
    u16* __restrict__ xb, u16* __restrict__ WqT, u16* __restrict__ WkT,
    u16* __restrict__ WvT, u16* __restrict__ WoT) {
  int bid = blockIdx.x;
  if (bid < 4096) {
    int id = bid * 256 + threadIdx.x;
    float4 v = x[id];
    ushort4 o;
    o.x = f2bf(v.x); o.y = f2bf(v.y); o.z = f2bf(v.z); o.w = f2bf(v.w);
    *(ushort4*)(xb + (size_t)id * 4) = o;
  } else {
    int id = (bid - 4096) * 256 + threadIdx.x;   // 589824 total
    const float* W; u16* WT; int K, idx;
    if (id < 262144)      { W = Wq; WT = WqT; K = 512; idx = id; }
    else if (id < 294912) { W = Wk; WT = WkT; K = 64;  idx = id - 262144; }
    else if (id < 327680) { W = Wv; WT = WvT; K = 64;  idx = id - 294912; }
    else                  { W = Wo; WT = WoT; K = 512; idx = id - 327680; }
    int n = idx / K, k = idx - n * K;
    WT[idx] = f2bf(W[k * 512 + n]);
  }
}

// ---------------- gate: gctx = bf16(ctx * sigmoid(relu(ctx@W1+b1)@W2+b2)) -----
__global__ __launch_bounds__(256) void gate_kernel(const float* __restrict__ ctx,
    const float* __restrict__ W1, const float* __restrict__ b1,
    const float* __restrict__ W2, const float* __restrict__ b2,
    u16* __restrict__ gctx) {
  int wave = threadIdx.x >> 6, lane = threadIdx.x & 63;
  int row = blockIdx.x * 4 + wave;            // 8192 rows total
  __shared__ float sc[4][64];
  float cv = ctx[(size_t)row * 64 + lane];
  sc[wave][lane] = cv;
  __syncthreads();
  float h = 0.f;
  if (lane < 32) {
    h = b1[lane];
    #pragma unroll
    for (int i = 0; i < 64; ++i) h += sc[wave][i] * W1[i * 32 + lane];
    h = fmaxf(h, 0.f) * W2[lane];
  }
  #pragma unroll
  for (int off = 32; off; off >>= 1) h += __shfl_xor(h, off);
  float g = 1.f / (1.f + __expf(-(h + b2[0])));
  gctx[(size_t)row * 64 + lane] = f2bf(cv * g);
}

// ---------------- big GEMM: 128x64 tile, BK=64 (two 32-k halves), gld16 -------
// C[M,N] = A[M,K] @ BT[N,K]^T, K=512. grid (N/64, M/128), 256 threads.
// MODE 0: bf16 out * scale. MODE 2: fp32 out + bias.
template<int MODE>
__global__ __launch_bounds__(256) void gemm128(const u16* __restrict__ A,
    const u16* __restrict__ BT, void* __restrict__ Cp,
    const float* __restrict__ bias, int N, float scale) {
  const int K = 512;
  const int lane = threadIdx.x & 63, wave = threadIdx.x >> 6;
  const int quad = lane >> 4, l16 = lane & 15;
  const int wr = wave >> 1, wc = wave & 1;
  const int m0 = blockIdx.y * 128, n0 = blockIdx.x * 64;

  __shared__ __align__(16) u16 As[2][128 * 32];   // [k-half][row*32]
  __shared__ __align__(16) u16 Bs[2][64 * 32];

  // staging source pointers: one gld16 = 16 rows x 32 k (1 KB)
  const u16* gA = A + (size_t)(m0 + wave * 32 + (lane >> 2)) * K + (lane & 3) * 8;
  const u16* gB = BT + (size_t)(n0 + wave * 16 + (lane >> 2)) * K + (lane & 3) * 8;

  facc acc[4][2] = {};

  for (int k0 = 0; k0 < K; k0 += 64) {
    if (k0) __syncthreads();
    gld16(gA + k0,           As[0] + wave * 1024);
    gld16(gA + 16 * K + k0,  As[0] + wave * 1024 + 512);
    gld16(gA + k0 + 32,          As[1] + wave * 1024);
    gld16(gA + 16 * K + k0 + 32, As[1] + wave * 1024 + 512);
    gld16(gB + k0,      Bs[0] + wave * 512);
    gld16(gB + k0 + 32, Bs[1] + wave * 512);
    __syncthreads();

    #pragma unroll
    for (int hh = 0; hh < 2; ++hh) {
      frag16 af[4], bf[2];
      #pragma unroll
      for (int rt = 0; rt < 4; ++rt)
        af[rt] = *(const frag16*)(As[hh] + (wr * 64 + rt * 16 + l16) * 32 + quad * 8);
      #pragma unroll
      for (int ct = 0; ct < 2; ++ct)
        bf[ct] = *(const frag16*)(Bs[hh] + (wc * 32 + ct * 16 + l16) * 32 + quad * 8);
      #pragma unroll
      for (int rt = 0; rt < 4; ++rt)
        #pragma unroll
        for (int ct = 0; ct < 2; ++ct)
          acc[rt][ct] = __builtin_amdgcn_mfma_f32_16x16x32_bf16(af[rt], bf[ct], acc[rt][ct], 0, 0, 0);
    }
  }

  #pragma unroll
  for (int rt = 0; rt < 4; ++rt) {
    #pragma unroll
    for (int ct = 0; ct < 2; ++ct) {
      int col = n0 + wc * 32 + ct * 16 + l16;
      int r0g = m0 + wr * 64 + rt * 16 + quad * 4;
      if (MODE == 0) {
        u16* C = (u16*)Cp;
        #pragma unroll
        for (int r = 0; r < 4; ++r)
          C[(size_t)(r0g + r) * N + col] = f2bf(acc[rt][ct][r] * scale);
      } else {
        float* C = (float*)Cp;
        float bv = bias[col];
        #pragma unroll
        for (int r = 0; r < 4; ++r)
          C[(size_t)(r0g + r) * N + col] = acc[rt][ct][r] + bv;
      }
    }
  }
}

// ---------------- fused k+v projection (K=64), fragment-packed epilogues ------
// Kp: 32x32x16 A-operand order (keys as M). Vp: same for V^T (dims as M).
__global__ __launch_bounds__(256) void gemm_kv(const u16* __restrict__ A,
    const u16* __restrict__ BkT, const u16* __restrict__ BvT,
    u16* __restrict__ Kp, u16* __restrict__ Vp) {
  const int Kd = 64, N = 512;
  int lane = threadIdx.x & 63, wave = threadIdx.x >> 6;
  int quad = lane >> 4, l16 = lane & 15;
  int wr = wave >> 1, wc = wave & 1;
  int rowBase = blockIdx.y * 64 + wr * 32;
  int colBase = blockIdx.x * 64 + wc * 32;
  facc ak[2][2] = {}, av[2][2] = {};
  const u16* a0 = A + (size_t)(rowBase + l16) * Kd + quad * 8;
  const u16* a1 = a0 + (size_t)16 * Kd;
  const u16* bk0 = BkT + (size_t)(colBase + l16) * Kd + quad * 8;
  const u16* bk1 = bk0 + (size_t)16 * Kd;
  const u16* bv0 = BvT + (size_t)(colBase + l16) * Kd + quad * 8;
  const u16* bv1 = bv0 + (size_t)16 * Kd;
  #pragma unroll
  for (int kk = 0; kk < Kd; kk += 32) {
    frag16 af0 = *(const frag16*)(a0 + kk);
    frag16 af1 = *(const frag16*)(a1 + kk);
    frag16 k0 = *(const frag16*)(bk0 + kk);
    frag16 k1 = *(const frag16*)(bk1 + kk);
    frag16 v0 = *(const frag16*)(bv0 + kk);
    frag16 v1 = *(const frag16*)(bv1 + kk);
    ak[0][0] = __builtin_amdgcn_mfma_f32_16x16x32_bf16(af0, k0, ak[0][0], 0, 0, 0);
    ak[0][1] = __builtin_amdgcn_mfma_f32_16x16x32_bf16(af0, k1, ak[0][1], 0, 0, 0);
    ak[1][0] = __builtin_amdgcn_mfma_f32_16x16x32_bf16(af1, k0, ak[1][0], 0, 0, 0);
    ak[1][1] = __builtin_amdgcn_mfma_f32_16x16x32_bf16(af1, k1, ak[1][1], 0, 0, 0);
    av[0][0] = __builtin_amdgcn_mfma_f32_16x16x32_bf16(af0, v0, av[0][0], 0, 0, 0);
    av[0][1] = __builtin_amdgcn_mfma_f32_16x16x32_bf16(af0, v1, av[0][1], 0, 0, 0);
    av[1][0] = __builtin_amdgcn_mfma_f32_16x16x32_bf16(af1, v0, av[1][0], 0, 0, 0);
    av[1][1] = __builtin_amdgcn_mfma_f32_16x16x32_bf16(af1, v1, av[1][1], 0, 0, 0);
  }
  #pragma unroll
  for (int rt = 0; rt < 2; ++rt) {
    #pragma unroll
    for (int ct = 0; ct < 2; ++ct) {
      int col = colBase + ct * 16 + l16;
      int r0g = rowBase + rt * 16 + quad * 4;
      int hh = col >> 6, d = col & 63;
      int b = r0g >> 11;
      // K-pack: frag lane = ((d>>3)&1)*32+(m&31), elem = d&7
      #pragma unroll
      for (int r = 0; r < 4; ++r) {
        int m = (r0g + r) & 2047;
        size_t addr = ((((size_t)(b * 8 + hh) * 64 + (m >> 5)) * 4 + (d >> 4)) * 64
                       + ((d >> 3) & 1) * 32 + (m & 31)) * 8 + (d & 7);
        Kp[addr] = f2bf(ak[rt][ct][r]);
      }
      // V-pack (V^T): 4 consecutive keys -> ushort4
      int m = r0g & 2047;
      size_t addr = ((((size_t)(b * 8 + hh) * 64 + (m >> 5)) * 4
                      + ((m >> 4) & 1) * 2 + (d >> 5)) * 64
                     + ((m >> 3) & 1) * 32 + (d & 31)) * 8 + (m & 7);
      ushort4 o;
      o.x = f2bf(av[rt][ct][0]); o.y = f2bf(av[rt][ct][1]);
      o.z = f2bf(av[rt][ct][2]); o.w = f2bf(av[rt][ct][3]);
      *(ushort4*)(Vp + addr) = o;
    }
  }
}

// ---------------- flash attention, 32x32 MFMA, packed K/V, key-split ----------
// qb: [B,N,512] bf16 pre-scaled by 0.125*log2(e). Kp/Vp: fragment-packed.
// Opart: [2][8192][512] fp32, Lpart: [2][8192*8] fp32 (per row PER HEAD).
// Register double-buffer: prefetch tile t+1's K/V frags during compute of t.
__global__ __launch_bounds__(256, 3) void attn_kernel(
    const u16* __restrict__ qb, const u16* __restrict__ Kp,
    const u16* __restrict__ Vp, float* __restrict__ Opart,
    float* __restrict__ Lpart) {
  const int lane = threadIdx.x & 63, wave = threadIdx.x >> 6;
  const int l32 = lane & 31;
  const int hi = lane >> 5;           // half-wave index
  const int bid = blockIdx.x;
  const int bh = bid & 31;            // low bits -> XCD locality
  const int qblk = (bid >> 5) & 15;
  const int js = bid >> 9;
  const int b = bh >> 3, h = bh & 7;
  const int q0 = (qblk * 4 + wave) * 32;
  const int rowg = b * 2048 + q0 + l32;

  // Q B-operand frags: n=q=l32, k=d = c*16 + hi*8 + jj
  const u16* qp = qb + (size_t)rowg * 512 + h * 64 + hi * 8;
  frag16 qf0 = *(const frag16*)(qp);
  frag16 qf1 = *(const frag16*)(qp + 16);
  frag16 qf2 = *(const frag16*)(qp + 32);
  frag16 qf3 = *(const frag16*)(qp + 48);

  facc16 O0 = {}, O1 = {};
  float lsum = 0.f;

  const size_t ts = 2048;  // u16 per 32-key tile (4 frags x 64 lanes x 8)
  const u16* kpb = Kp + (size_t)(bh * 64 + js * 32) * ts + lane * 8;
  const u16* vpb = Vp + (size_t)(bh * 64 + js * 32) * ts + lane * 8;

  frag16 kf[4], vf[4];
  #pragma unroll
  for (int i = 0; i < 4; ++i) {
    kf[i] = *(const frag16*)(kpb + i * 512);
    vf[i] = *(const frag16*)(vpb + i * 512);
  }

  for (int t = 0; t < 32; ++t) {
    int tn = (t < 31) ? t + 1 : 31;
    const u16* ktn = kpb + (size_t)tn * ts;
    const u16* vtn = vpb + (size_t)tn * ts;
    frag16 nkf[4], nvf[4];
    #pragma unroll
    for (int i = 0; i < 4; ++i) {
      nkf[i] = *(const frag16*)(ktn + i * 512);
      nvf[i] = *(const frag16*)(vtn + i * 512);
    }

    facc16 S = {};
    S = __builtin_amdgcn_mfma_f32_32x32x16_bf16(kf[0], qf0, S, 0, 0, 0);
    S = __builtin_amdgcn_mfma_f32_32x32x16_bf16(kf[1], qf1, S, 0, 0, 0);
    S = __builtin_amdgcn_mfma_f32_32x32x16_bf16(kf[2], qf2, S, 0, 0, 0);
    S = __builtin_amdgcn_mfma_f32_32x32x16_bf16(kf[3], qf3, S, 0, 0, 0);

    float e[16];
    #pragma unroll
    for (int r = 0; r < 16; ++r) e[r] = __builtin_amdgcn_exp2f(S[r]);
    #pragma unroll
    for (int r = 0; r < 16; ++r) lsum += e[r];

    // S^T C-layout -> P B-operand layout: pack own, then half-wave dword swap.
    unsigned pu[2][4];
    #pragma unroll
    for (int c = 0; c < 2; ++c) {
      const float* ee = e + c * 8;
      unsigned L0 = pkbf(ee[0], ee[1]);
      unsigned L1 = pkbf(ee[2], ee[3]);
      unsigned H0 = pkbf(ee[4], ee[5]);
      unsigned H1 = pkbf(ee[6], ee[7]);
      unsigned Y0 = hi ? L0 : H0;
      unsigned Y1 = hi ? L1 : H1;
      unsigned X0 = (unsigned)__shfl_xor((int)Y0, 32);
      unsigned X1 = (unsigned)__shfl_xor((int)Y1, 32);
      pu[c][0] = hi ? X0 : L0;
      pu[c][1] = hi ? X1 : L1;
      pu[c][2] = hi ? H0 : X0;
      pu[c][3] = hi ? H1 : X1;
    }
    frag16 P0 = *(frag16*)&pu[0][0];
    frag16 P1 = *(frag16*)&pu[1][0];

    O0 = __builtin_amdgcn_mfma_f32_32x32x16_bf16(vf[0], P0, O0, 0, 0, 0);
    O0 = __builtin_amdgcn_mfma_f32_32x32x16_bf16(vf[2], P1, O0, 0, 0, 0);
    O1 = __builtin_amdgcn_mfma_f32_32x32x16_bf16(vf[1], P0, O1, 0, 0, 0);
    O1 = __builtin_amdgcn_mfma_f32_32x32x16_bf16(vf[3], P1, O1, 0, 0, 0);

    #pragma unroll
    for (int i = 0; i < 4; ++i) { kf[i] = nkf[i]; vf[i] = nvf[i]; }
  }

  lsum += __shfl_xor(lsum, 32);

  // O^T C-layout: col=q=l32, row=d = dt*32 + 8*(reg>>2) + 4*hi + (reg&3)
  float* op = Opart + ((size_t)js * 8192 + rowg) * 512 + h * 64;
  #pragma unroll
  for (int dt = 0; dt < 2; ++dt) {
    #pragma unroll
    for (int rq = 0; rq < 4; ++rq) {
      float4 v;
      if (dt == 0) { v.x = O0[rq*4]; v.y = O0[rq*4+1]; v.z = O0[rq*4+2]; v.w = O0[rq*4+3]; }
      else         { v.x = O1[rq*4]; v.y = O1[rq*4+1]; v.z = O1[rq*4+2]; v.w = O1[rq*4+3]; }
      int d0 = dt * 32 + 8 * rq + 4 * hi;
      *(float4*)(op + d0) = v;
    }
  }
  // L is per (row, head): [2][8192*8]
  if (!hi) Lpart[(size_t)js * 65536 + (size_t)rowg * 8 + h] = lsum;
}

// ---------------- combine the two key-split partials -> bf16 ------------------
__global__ __launch_bounds__(256) void combine_kernel(const float* __restrict__ Opart,
    const float* __restrict__ Lpart, u16* __restrict__ ob) {
  int id = blockIdx.x * 256 + threadIdx.x;   // 8192*128
  int row = id >> 7, c4 = (id & 127) * 4;
  int hh = c4 >> 6;
  size_t o = (size_t)row * 512 + c4;
  const float4 o0 = *(const float4*)(Opart + o);
  const float4 o1 = *(const float4*)(Opart + (size_t)8192 * 512 + o);
  float rl = 1.f / (Lpart[(size_t)row * 8 + hh] + Lpart[65536 + (size_t)row * 8 + hh]);
  ushort4 u;
  u.x = f2bf((o0.x + o1.x) * rl);
  u.y = f2bf((o0.y + o1.y) * rl);
  u.z = f2bf((o0.z + o1.z) * rl);
  u.w = f2bf((o0.w + o1.w) * rl);
  *(ushort4*)(ob + o) = u;
}

// ---------------- launch ------------------------------------------------------
extern "C" void kernel_launch(void* const* d_in, const int* in_sizes, int n_in,
                              void* d_out, int out_size, void* d_ws, size_t ws_size,
                              hipStream_t stream) {
  const float* x   = (const float*)d_in[0];
  const float* ctx = (const float*)d_in[1];
  const float* Wq  = (const float*)d_in[2];
  const float* Wk  = (const float*)d_in[3];
  const float* Wv  = (const float*)d_in[4];
  const float* W1  = (const float*)d_in[5];
  const float* b1  = (const float*)d_in[6];
  const float* W2  = (const float*)d_in[7];
  const float* b2  = (const float*)d_in[8];
  const float* Wo  = (const float*)d_in[9];
  const float* bo  = (const float*)d_in[10];
  float* out = (float*)d_out;

  char* ws = (char*)d_ws;
  size_t off = 0;
  auto alloc = [&](size_t bytes) {
    char* p = ws + off;
    off += (bytes + 255) & ~(size_t)255;
    return p;
  };
  u16* xb    = (u16*)alloc(8192ull * 512 * 2);
  u16* qb    = (u16*)alloc(8192ull * 512 * 2);
  u16* Kp    = (u16*)alloc(8192ull * 512 * 2);
  u16* Vp    = (u16*)alloc(8192ull * 512 * 2);
  u16* ob    = (u16*)alloc(8192ull * 512 * 2);
  u16* gctx  = (u16*)alloc(8192ull * 64 * 2);
  u16* WqT   = (u16*)alloc(512ull * 512 * 2);
  u16* WkT   = (u16*)alloc(512ull * 64 * 2);
  u16* WvT   = (u16*)alloc(512ull * 64 * 2);
  u16* WoT   = (u16*)alloc(512ull * 512 * 2);
  float* Opart = (float*)alloc(2ull * 8192 * 512 * 4);
  float* Lpart = (float*)alloc(2ull * 65536 * 4);

  prep_kernel<<<6400, 256, 0, stream>>>((const float4*)x, Wq, Wk, Wv, Wo,
                                        xb, WqT, WkT, WvT, WoT);
  gate_kernel<<<2048, 256, 0, stream>>>(ctx, W1, b1, W2, b2, gctx);

  // q = x @ Wq, scaled by (1/sqrt(64)) * log2(e) for exp2-softmax
  gemm128<0><<<dim3(8, 64), 256, 0, stream>>>(xb, WqT, qb, nullptr, 512,
                                              0.125f * 1.4426950408889634f);
  // k,v = gctx @ {Wk,Wv} -> fragment-packed (fused)
  gemm_kv<<<dim3(8, 128), 256, 0, stream>>>(gctx, WkT, WvT, Kp, Vp);

  attn_kernel<<<1024, 256, 0, stream>>>(qb, Kp, Vp, Opart, Lpart);
  combine_kernel<<<4096, 256, 0, stream>>>(Opart, Lpart, ob);

  // out = ob @ Wo + bo  (fp32)
  gemm128<2><<<dim3(8, 64), 256, 0, stream>>>(ob, WoT, out, bo, 512, 1.f);
}